// Round 2
// baseline (1703.404 us; speedup 1.0000x reference)
//
#include <hip/hip_runtime.h>
#include <stdint.h>

#define HID   128
#define OUT   4096
#define NWG   16
#define SLICE 256          // OUT / NWG
#define NT    256
#define LD    132          // padded leading dim for the (startup-only) LDS staging

// ---------------- Kernel 1: per-block partials of xW1 = clip(x,0,1) @ W1 -----------
// No atomics: block b writes xw1p[b*128 + c]; k_ep reduces the 256 partials once.
__global__ __launch_bounds__(NT) void k_xw1(const float* __restrict__ x,
                                            const float* __restrict__ W1,
                                            float* __restrict__ xw1p) {
  __shared__ float red[NT];
  const int t = threadIdx.x;
  const int c = t & (HID - 1);
  const int half = t >> 7;
  const int row0 = blockIdx.x * 256 + half * 128;
  float acc = 0.f;
#pragma unroll 4
  for (int rr = 0; rr < 128; ++rr) {
    const int r = row0 + rr;
    float rx = fminf(fmaxf(x[r], 0.f), 1.f);
    acc = fmaf(rx, W1[(size_t)r * HID + c], acc);
  }
  red[t] = acc;
  __syncthreads();
  if (t < HID) xw1p[blockIdx.x * HID + t] = red[t] + red[t + HID];
}

// ---------------- Kernel 2: persistent EP iteration kernel --------------------------
// 16 WGs; each WG's 256-column W2 slice lives entirely in REGISTERS, in two
// partitions: regB (rows 4l..4l+3 x 32 cols of group jg) for W2@r_o, and
// regA (own column t) for r_h@W2. LDS is used only at startup (distribution)
// and for tiny per-iteration broadcasts (r_h, r_o, 8-way g_h reduce).
// Cross-WG sync: per-WG release flag on its own cacheline, polled in parallel.
__global__ __launch_bounds__(NT, 1) void k_ep(const float* __restrict__ W2,
                                              const float* __restrict__ b_h,
                                              const float* __restrict__ b_out,
                                              const float* __restrict__ h0,
                                              const float* __restrict__ o0,
                                              const int* __restrict__ n_iter_p,
                                              const float* __restrict__ eps_p,
                                              const float* __restrict__ xw1p,  // [256][HID]
                                              float* __restrict__ pbuf0,       // [2][NWG][HID]
                                              int* __restrict__ flags,         // NWG lines, 32-int spaced
                                              float* __restrict__ out) {
  __shared__ float w2t[SLICE * LD];   // startup staging only (col-major)
  __shared__ float rh_s[HID];
  __shared__ float ro_s[SLICE];
  __shared__ float red[8 * HID];

  const int t  = threadIdx.x;
  const int wg = blockIdx.x;
  const int jbase = wg * SLICE;
  const int l  = t & 31;              // row quad: rows 4l..4l+3
  const int jg = t >> 5;              // 8 col-groups of 32
  const int n_iter = *n_iter_p;
  const float eps  = *eps_p;

  // ---- stage W2 slice into LDS (coalesced global reads), then distribute to regs
#pragma unroll 1
  for (int k = 0; k < (SLICE * HID) / NT; ++k) {
    const int idx = t + k * NT;
    const int j = idx & (SLICE - 1);
    const int i = idx >> 8;
    w2t[j * LD + i] = W2[(size_t)i * OUT + jbase + j];
  }
  __syncthreads();

  float4 regB[32];                    // Pass-B partition: col jg*32+jj, rows 4l..4l+3
#pragma unroll
  for (int jj = 0; jj < 32; ++jj)
    regB[jj] = *(const float4*)&w2t[(jg * 32 + jj) * LD + 4 * l];

  float4 regA[32];                    // Pass-A partition: own column t, all 128 rows
#pragma unroll
  for (int q = 0; q < 32; ++q)
    regA[q] = *(const float4*)&w2t[t * LD + 4 * q];

  // ---- per-thread state
  float hh = 0.f, mh = 0.f, vh = 0.f, bhx = 0.f;   // h replicated per WG (t<128)
  if (t < HID) {
    float s = 0.f;
#pragma unroll 8
    for (int b = 0; b < 256; ++b) s += xw1p[b * HID + t];
    bhx = b_h[t] + s;
    hh  = h0[t];
    rh_s[t] = fminf(fmaxf(hh, 0.f), 1.f);
  }
  float oo = o0[jbase + t];
  float mo = 0.f, vo = 0.f;
  const float bo = b_out[jbase + t];
  ro_s[t] = fminf(fmaxf(oo, 0.f), 1.f);
  __syncthreads();

  float bp1 = 1.f, bp2 = 1.f;

  for (int it = 0; it < n_iter; ++it) {
    bp1 *= 0.9f; bp2 *= 0.999f;
    const float c1 = 1.f / (1.f - bp1);
    const float c2 = 1.f / (1.f - bp2);
    float* pbuf = pbuf0 + (size_t)(it & 1) * NWG * HID;

    // ---- Pass B: g_h partials from registers (uses OLD r_o) ----
    {
      float a0 = 0.f, a1 = 0.f, a2 = 0.f, a3 = 0.f;
#pragma unroll
      for (int jj = 0; jj < 32; ++jj) {
        const float ro = ro_s[jg * 32 + jj];   // 2 addrs/wave -> free broadcast
        a0 = fmaf(regB[jj].x, ro, a0); a1 = fmaf(regB[jj].y, ro, a1);
        a2 = fmaf(regB[jj].z, ro, a2); a3 = fmaf(regB[jj].w, ro, a3);
      }
      *(float4*)&red[jg * HID + 4 * l] = make_float4(a0, a1, a2, a3);
    }
    __syncthreads();
    if (t < HID) {
      float p = 0.f;
#pragma unroll
      for (int g = 0; g < 8; ++g) p += red[g * HID + t];
      __hip_atomic_store(&pbuf[wg * HID + t], p, __ATOMIC_RELAXED, __HIP_MEMORY_SCOPE_AGENT);
    }
    __syncthreads();                  // partial stores drained before flag
    if (t == 0) {
      __threadfence();
      __hip_atomic_store(&flags[wg * 32], it + 1, __ATOMIC_RELEASE, __HIP_MEMORY_SCOPE_AGENT);
    }

    // ---- Pass A (overlaps flag propagation): g_o + Adam(o) from registers ----
    {
      float s = 0.f;
#pragma unroll
      for (int q = 0; q < 32; ++q) {
        const float4 rh = *(const float4*)&rh_s[4 * q];   // same addr all lanes
        s = fmaf(regA[q].x, rh.x, s); s = fmaf(regA[q].y, rh.y, s);
        s = fmaf(regA[q].z, rh.z, s); s = fmaf(regA[q].w, rh.w, s);
      }
      const float ro_old = fminf(fmaxf(oo, 0.f), 1.f);
      const float g = (oo >= 0.f && oo <= 1.f) ? (ro_old - bo - s) : 0.f;
      mo = 0.9f * mo + 0.1f * g;
      vo = 0.999f * vo + 0.001f * g * g;
      oo -= eps * (mo * c1) / (sqrtf(vo * c2) + 1e-8f);
      ro_s[t] = fminf(fmaxf(oo, 0.f), 1.f);   // next reader is Pass B after barriers
    }

    // ---- wait for all WGs: 16 parallel flag polls in wave 0 ----
    if (t < NWG) {
      while (__hip_atomic_load(&flags[t * 32], __ATOMIC_ACQUIRE, __HIP_MEMORY_SCOPE_AGENT) < it + 1) {}
    }
    __syncthreads();

    // ---- g_h gather + Adam(h), replicated in every WG ----
    if (t < HID) {
      float gsum = 0.f;
#pragma unroll
      for (int w = 0; w < NWG; ++w)
        gsum += __hip_atomic_load(&pbuf[w * HID + t], __ATOMIC_RELAXED, __HIP_MEMORY_SCOPE_AGENT);
      const float rh_old = fminf(fmaxf(hh, 0.f), 1.f);
      const float g = (hh >= 0.f && hh <= 1.f) ? (rh_old - bhx - gsum) : 0.f;
      mh = 0.9f * mh + 0.1f * g;
      vh = 0.999f * vh + 0.001f * g * g;
      hh -= eps * (mh * c1) / (sqrtf(vh * c2) + 1e-8f);
      rh_s[t] = fminf(fmaxf(hh, 0.f), 1.f);
    }
    __syncthreads();
  }

  out[jbase + t] = oo;
}

// ---------------- launcher ----------------------------------------------------------
extern "C" void kernel_launch(void* const* d_in, const int* in_sizes, int n_in,
                              void* d_out, int out_size, void* d_ws, size_t ws_size,
                              hipStream_t stream) {
  const float* x     = (const float*)d_in[0];
  const float* W1    = (const float*)d_in[1];
  const float* W2    = (const float*)d_in[2];
  // d_in[3] = b_in (unused by the reference)
  const float* b_h   = (const float*)d_in[4];
  const float* b_out = (const float*)d_in[5];
  const float* h0    = (const float*)d_in[6];
  const float* o0    = (const float*)d_in[7];
  const int*   nit   = (const int*)d_in[8];
  const float* eps   = (const float*)d_in[9];

  int*   flags = (int*)d_ws;                            // [0, 2048): 16 flags, 128B apart
  float* pbuf  = (float*)((char*)d_ws + 4096);          // 2 x 16 x 128 floats
  float* xw1p  = (float*)((char*)d_ws + 32768);         // 256 x 128 floats (128 KB)
  float* out   = (float*)d_out;

  hipMemsetAsync(d_ws, 0, 2048, stream);                // zero flags only

  k_xw1<<<dim3(256), dim3(NT), 0, stream>>>(x, W1, xw1p);
  k_ep<<<dim3(NWG), dim3(NT), 0, stream>>>(W2, b_h, b_out, h0, o0, nit, eps,
                                           xw1p, pbuf, flags, out);
}

// Round 3
// 1584.757 us; speedup vs baseline: 1.0749x; 1.0749x over previous
//
#include <hip/hip_runtime.h>
#include <stdint.h>

#define HID   128
#define OUT   4096
#define NWG   16          // persistent EP workgroups (each: 256-col slice of W2)
#define SLICE 256         // OUT / NWG
#define NT    256
#define NXB   128         // one-shot xW1 worker blocks
#define RPX   512         // rows per xW1 block (65536 / 128)

typedef unsigned long long u64;

__device__ __forceinline__ u64 pk(uint32_t tag, float v) {
  return ((u64)tag << 32) | (u64)__float_as_uint(v);
}

// Single fused kernel. blockIdx < NWG: persistent EP workgroup.
// blockIdx >= NWG: one-shot xW1 partial worker (tagged publish, no memset needed).
__global__ __launch_bounds__(NT, 1) void k_all(
    const float* __restrict__ x,
    const float* __restrict__ W1,
    const float* __restrict__ W2,
    const float* __restrict__ b_h,
    const float* __restrict__ b_out,
    const float* __restrict__ h0,
    const float* __restrict__ o0,
    const int* __restrict__ n_iter_p,
    const float* __restrict__ eps_p,
    u64* __restrict__ pbuf,   // [2][NWG][HID] tagged h-gradient partials
    u64* __restrict__ xw1p,   // [NXB][HID] tagged xW1 partials
    float* __restrict__ out) {

  __shared__ float w2r[HID * SLICE];  // 128 KB row-major W2 slice (EP only)
  __shared__ float red[8 * HID];      // 4 KB scratch: PassB red / PassA red / worker red
  __shared__ float rh_s[HID];
  __shared__ float ro_s[SLICE];

  const int t = threadIdx.x;

  if (blockIdx.x >= NWG) {
    // ---------------- xW1 worker: partial of clip(x,0,1) @ W1 over 512 rows ------
    const int b = blockIdx.x - NWG;
    const int c4 = (t & 31) * 4;
    const int rseg = t >> 5;
    const int r0 = b * RPX + rseg * 64;
    float4 acc = make_float4(0.f, 0.f, 0.f, 0.f);
#pragma unroll 8
    for (int k = 0; k < 64; ++k) {
      const int r = r0 + k;
      const float rx = fminf(fmaxf(x[r], 0.f), 1.f);
      const float4 w = *(const float4*)&W1[(size_t)r * HID + c4];
      acc.x = fmaf(rx, w.x, acc.x); acc.y = fmaf(rx, w.y, acc.y);
      acc.z = fmaf(rx, w.z, acc.z); acc.w = fmaf(rx, w.w, acc.w);
    }
    *(float4*)&red[rseg * HID + c4] = acc;
    __syncthreads();
    if (t < HID) {
      const float s = ((red[t] + red[HID + t]) + (red[2*HID + t] + red[3*HID + t]))
                    + ((red[4*HID + t] + red[5*HID + t]) + (red[6*HID + t] + red[7*HID + t]));
      __hip_atomic_store(&xw1p[b * HID + t], pk(1u, s),
                         __ATOMIC_RELAXED, __HIP_MEMORY_SCOPE_AGENT);
    }
    return;
  }

  // ---------------- persistent EP workgroup ---------------------------------------
  const int wg = blockIdx.x;
  const int jbase = wg * SLICE;
  const int l  = t & 31;   // Pass B: row quad 4l..4l+3
  const int jg = t >> 5;   // Pass B: col group of 32
  const int l2 = t & 63;   // Pass A: col quad 4*l2
  const int ig = t >> 6;   // Pass A: row group of 32
  const int n_iter = *n_iter_p;
  const float eps  = *eps_p;

  // stage W2 slice ROW-major (coalesced global, stride-1 conflict-free LDS)
#pragma unroll
  for (int k = 0; k < 32; ++k) {
    const int f = k * NT + t;          // float4 index
    const int i = f >> 6;              // 64 float4 per row
    const int j4 = (f & 63) * 4;
    *(float4*)&w2r[i * SLICE + j4] = *(const float4*)&W2[(size_t)i * OUT + jbase + j4];
  }

  // Pass-B register partition: col jg*32+jj, rows 4l..4l+3 (from global, L2-hot)
  float4 regB[32];
  {
    const float* bp = W2 + (size_t)(4 * l) * OUT + jbase + jg * 32;
#pragma unroll
    for (int jj = 0; jj < 32; ++jj)
      regB[jj] = make_float4(bp[jj], bp[jj + OUT], bp[jj + 2 * OUT], bp[jj + 3 * OUT]);
  }

  // gather xW1 partials (tag-polled, FIXED summation order -> identical in all WGs)
  float bhx = 0.f, hh = 0.f, mh = 0.f, vh = 0.f;
  if (t < HID) {
    float s = 0.f;
#pragma unroll 1
    for (int ch = 0; ch < 8; ++ch) {
      float vals[16]; unsigned got = 0u;
      while (got != 0xFFFFu) {
#pragma unroll
        for (int k = 0; k < 16; ++k) if (!(got & (1u << k))) {
          const u64 v = __hip_atomic_load(&xw1p[(ch * 16 + k) * HID + t],
                                          __ATOMIC_RELAXED, __HIP_MEMORY_SCOPE_AGENT);
          if ((uint32_t)(v >> 32) == 1u) { vals[k] = __uint_as_float((uint32_t)v); got |= 1u << k; }
        }
        if (got != 0xFFFFu) __builtin_amdgcn_s_sleep(1);
      }
#pragma unroll
      for (int k = 0; k < 16; ++k) s += vals[k];
    }
    bhx = b_h[t] + s;
    hh  = h0[t];
    rh_s[t] = fminf(fmaxf(hh, 0.f), 1.f);
  }
  float oo = o0[jbase + t];
  float mo = 0.f, vo = 0.f;
  const float bo = b_out[jbase + t];
  ro_s[t] = fminf(fmaxf(oo, 0.f), 1.f);
  __syncthreads();

  float bp1 = 1.f, bp2 = 1.f;

  for (int it = 0; it < n_iter; ++it) {
    bp1 *= 0.9f; bp2 *= 0.999f;
    const float c1 = 1.f / (1.f - bp1);
    const float c2 = 1.f / (1.f - bp2);
    u64* pb = pbuf + (size_t)(it & 1) * (NWG * HID);
    const uint32_t tag = (uint32_t)(it + 1);

    // ---- Pass B from registers: partial of W2 @ r_o (OLD r_o) ----
    {
      float a0 = 0.f, a1 = 0.f, a2 = 0.f, a3 = 0.f;
#pragma unroll
      for (int jj = 0; jj < 32; ++jj) {
        const float ro = ro_s[jg * 32 + jj];     // 2 addrs/wave -> free broadcast
        a0 = fmaf(regB[jj].x, ro, a0); a1 = fmaf(regB[jj].y, ro, a1);
        a2 = fmaf(regB[jj].z, ro, a2); a3 = fmaf(regB[jj].w, ro, a3);
      }
      *(float4*)&red[jg * HID + 4 * l] = make_float4(a0, a1, a2, a3);
    }
    __syncthreads();
    if (t < HID) {
      const float p = ((red[t] + red[HID + t]) + (red[2*HID + t] + red[3*HID + t]))
                    + ((red[4*HID + t] + red[5*HID + t]) + (red[6*HID + t] + red[7*HID + t]));
      __hip_atomic_store(&pb[wg * HID + t], pk(tag, p),
                         __ATOMIC_RELAXED, __HIP_MEMORY_SCOPE_AGENT);   // data rides with tag
    }
    __syncthreads();   // red now reusable by Pass A

    // ---- Pass A from LDS (hidden in the sync window): r_h @ W2 + Adam(o) ----
    {
      float b0 = 0.f, b1 = 0.f, b2 = 0.f, b3 = 0.f;
      const int col0 = 4 * l2;
#pragma unroll
      for (int k = 0; k < 32; ++k) {
        const int i = ig * 32 + k;
        const float4 w = *(const float4*)&w2r[i * SLICE + col0];  // stride-1 b128, conflict-free
        const float rh = rh_s[i];                                 // wave-uniform broadcast
        b0 = fmaf(w.x, rh, b0); b1 = fmaf(w.y, rh, b1);
        b2 = fmaf(w.z, rh, b2); b3 = fmaf(w.w, rh, b3);
      }
      *(float4*)&red[ig * SLICE + col0] = make_float4(b0, b1, b2, b3);
    }
    __syncthreads();
    {
      const float s = (red[t] + red[SLICE + t]) + (red[2*SLICE + t] + red[3*SLICE + t]);
      const float ro_old = fminf(fmaxf(oo, 0.f), 1.f);
      const float g = (oo >= 0.f && oo <= 1.f) ? (ro_old - bo - s) : 0.f;
      mo = 0.9f * mo + 0.1f * g;
      vo = 0.999f * vo + 0.001f * g * g;
      oo -= eps * (mo * c1) / (sqrtf(vo * c2) + 1e-8f);
      ro_s[t] = fminf(fmaxf(oo, 0.f), 1.f);   // next reader: Pass B after loop-end sync
    }

    // ---- poll tagged partials from all 16 WGs, then Adam(h) (replicated) ----
    if (t < HID) {
      float gv[16]; unsigned got = 0u;
      while (got != 0xFFFFu) {
#pragma unroll
        for (int w = 0; w < 16; ++w) if (!(got & (1u << w))) {
          const u64 v = __hip_atomic_load(&pb[w * HID + t],
                                          __ATOMIC_RELAXED, __HIP_MEMORY_SCOPE_AGENT);
          if ((uint32_t)(v >> 32) == tag) { gv[w] = __uint_as_float((uint32_t)v); got |= 1u << w; }
        }
      }
      const float gsum = (((gv[0] + gv[1]) + (gv[2] + gv[3])) + ((gv[4] + gv[5]) + (gv[6] + gv[7])))
                       + (((gv[8] + gv[9]) + (gv[10] + gv[11])) + ((gv[12] + gv[13]) + (gv[14] + gv[15])));
      const float rh_old = fminf(fmaxf(hh, 0.f), 1.f);
      const float g = (hh >= 0.f && hh <= 1.f) ? (rh_old - bhx - gsum) : 0.f;
      mh = 0.9f * mh + 0.1f * g;
      vh = 0.999f * vh + 0.001f * g * g;
      hh -= eps * (mh * c1) / (sqrtf(vh * c2) + 1e-8f);
      rh_s[t] = fminf(fmaxf(hh, 0.f), 1.f);
    }
    __syncthreads();
  }

  out[jbase + t] = oo;
}

// ---------------- launcher ----------------------------------------------------------
extern "C" void kernel_launch(void* const* d_in, const int* in_sizes, int n_in,
                              void* d_out, int out_size, void* d_ws, size_t ws_size,
                              hipStream_t stream) {
  const float* x     = (const float*)d_in[0];
  const float* W1    = (const float*)d_in[1];
  const float* W2    = (const float*)d_in[2];
  // d_in[3] = b_in (unused by the reference)
  const float* b_h   = (const float*)d_in[4];
  const float* b_out = (const float*)d_in[5];
  const float* h0    = (const float*)d_in[6];
  const float* o0    = (const float*)d_in[7];
  const int*   nit   = (const int*)d_in[8];
  const float* eps   = (const float*)d_in[9];

  u64*   pbuf = (u64*)d_ws;                         // [2][16][128] u64 = 32 KB
  u64*   xw1p = (u64*)((char*)d_ws + 32768);        // [128][128] u64 = 128 KB
  float* out  = (float*)d_out;

  // no memset: 0xAA-poisoned tags never match (xw1 tag=1, iter tags=1..n_iter)
  k_all<<<dim3(NWG + NXB), dim3(NT), 0, stream>>>(x, W1, W2, b_h, b_out, h0, o0,
                                                  nit, eps, pbuf, xw1p, out);
}